// Round 11
// baseline (462.510 us; speedup 1.0000x reference)
//
#include <hip/hip_runtime.h>

#define HW 9216      // 96*96
#define NBATCH 512

__device__ __forceinline__ float clampf(float v, float lo, float hi){ return fminf(fmaxf(v, lo), hi); }

__device__ __forceinline__ float waveSum(float v){
#pragma unroll
  for (int o = 32; o; o >>= 1) v += __shfl_xor(v, o, 64);
  return v;
}

// ---------------- weighted MSE ----------------
__global__ __launch_bounds__(256) void mse_kernel(const float4* __restrict__ yp,
                                                  const float4* __restrict__ yt,
                                                  const float4* __restrict__ wm,
                                                  float* __restrict__ partial){
  __shared__ float red[4];
  const int tid = threadIdx.x;
  int idx = blockIdx.x * 256 + tid;
  float s = 0.f;
#pragma unroll
  for (int u = 0; u < 9; ++u){            // 512 blocks * 256 thr * 9 * 4 = 4718592 elements
    float4 a = yp[idx], b = yt[idx], w = wm[idx];
    float dx = a.x-b.x, dy = a.y-b.y, dz = a.z-b.z, dw = a.w-b.w;
    s += dx*dx*w.x + dy*dy*w.y + dz*dz*w.z + dw*dw*w.w;
    idx += 131072;
  }
  s = waveSum(s);
  if ((tid & 63) == 0) red[tid >> 6] = s;
  __syncthreads();
  if (tid == 0) partial[blockIdx.x] = red[0]+red[1]+red[2]+red[3];
}

// ---------------- FUSED ellipticity + reblur-conv ----------------
// r10 failed because DYNAMIC LDS hid the 4-blocks/CU occupancy cap from the
// register allocator: it budgeted 40 VGPRs (max-occupancy target) and spilled
// the ellip pixel array (WRITE_SIZE 32.5MB). STATIC 39960B LDS makes the cap
// visible -> budget rises to ~85 (6 waves/EU) -> both paths fit (ellip ~64,
// conv ~40), zero spill. Structure otherwise identical to r10: 2048 blocks,
// parity-interleaved (even=ellip, odd=conv); ellip active on tid<256 with r8's
// proven geometry (36px/thread as 18 asm-pinned f16 pairs), tid>=256 runs a
// barrier-count-matched skeleton.
__global__ __launch_bounds__(384, 6)
void fused_kernel(const float* __restrict__ y_true,
                  const float* __restrict__ y_pred,
                  const float* __restrict__ kimg,
                  const float* __restrict__ blurred,
                  const float* __restrict__ wmap,
                  float2* __restrict__ ebuf,       // [1024]
                  float* __restrict__ convp){      // [1024]
  __shared__ float smem[9990];                     // 39960 B, static: visible to regalloc
  typedef __fp16 half2_t __attribute__((ext_vector_type(2)));
  const int tid = threadIdx.x;
  const int bid = blockIdx.x;
  const int id  = bid >> 1;
  const int wave = tid >> 6, lane = tid & 63;

  if ((bid & 1) == 0){
    // ================= ellip path (active: tid<256, 4 waves) =================
    float (*wred)[4] = (float(*)[4])smem;          // [7][4]
    float* tred = smem + 28;                       // [4]
    if (tid < 256){
      const int d = id >> 9;
      const int b = id & 511;
      const int tx = tid & 31, ty = tid >> 5;      // ty 0..7; rows ty+8k, cols tx+32c

      const float* src = (d ? y_pred : y_true) + (size_t)b * HW + ty * 96 + tx;

      unsigned px2[6][3];
      float tot = 0.f;
#pragma unroll
      for (int jj = 0; jj < 6; ++jj){
#pragma unroll
        for (int c = 0; c < 3; ++c){
          float ve = src[jj*1536 + c*32];
          float vo = src[jj*1536 + 768 + c*32];
          tot += ve + vo;                          // exact f32 total
          half2_t pk = __builtin_amdgcn_cvt_pkrtz(ve, vo);
          unsigned u = __builtin_bit_cast(unsigned, pk);
          asm volatile("" : "+v"(u));              // pin in VGPR (r3 remat fix)
          px2[jj][c] = u;
        }
      }
      tot = waveSum(tot);
      if (lane == 0) tred[wave] = tot;
      __syncthreads();
      float total;
      { float4 t = *reinterpret_cast<const float4*>(&tred[0]); total = (t.x+t.y)+(t.z+t.w); }
      __syncthreads();

      const float Ya00 = (float)ty - 47.5f;
      float Xa[3];
#pragma unroll
      for (int c = 0; c < 3; ++c){ Xa[c] = (float)(tx + 32*c) - 47.5f; }

      float zx=4.f, zy=4.f, axy=0.f, mux=0.f, muy=0.f, back=0.f, e1=0.f, e2=0.f;
      const float LOG2E = 1.4426950408889634f;
      const float NQLO  = -43.280851226668906f;    // -30*log2(e)

      for (int it = 0; it < 40; ++it){
        float axyc = clampf(axy, -10.f, 10.f);
        float prod = zx*zy;
        float adn  = sqrtf(prod);                  // = ax*ay >= 1
        float rca  = __builtin_amdgcn_rcpf(adn);
        float ar   = clampf(axyc*rca, -0.95f, 0.95f);
        float omr  = fmaf(-ar, ar, 1.f);           // >= 0.0975
        float A    = 0.15915494309189535f * rca * __builtin_amdgcn_rsqf(omr);
        float invq = __builtin_amdgcn_rcpf(2.f*omr*prod);
        float a1 = -LOG2E*zy*invq;
        float a2 = -LOG2E*zx*invq;
        float a3 = (2.f*LOG2E)*axyc*invq;
        float cX2[3], cX3[3];
#pragma unroll
        for (int c = 0; c < 3; ++c){
          float Xc = Xa[c] - mux;
          cX2[c] = a1*Xc*Xc;
          cX3[c] = a3*Xc;
        }
        float S0[3] = {0.f,0.f,0.f}, SY[3] = {0.f,0.f,0.f};
        float tYY = 0.f, tkk = 0.f;
#pragma unroll
        for (int jj = 0; jj < 6; ++jj){
          float Yae = Ya00 + 16.f*jj;
          float Yao = Yae + 8.f;
          float Yce = Yae - muy, Yco = Yao - muy;
          float he = a2*Yce*Yce, ho = a2*Yco*Yco;
          float rse = 0.f, rso = 0.f;
#pragma unroll
          for (int c = 0; c < 3; ++c){
            half2_t pk = __builtin_bit_cast(half2_t, px2[jj][c]);
            float pe = (float)pk.x, po = (float)pk.y;
            {
              float nq = fmaf(cX3[c], Yce, he + cX2[c]);
              float e  = __builtin_amdgcn_exp2f(fminf(fmaxf(nq, NQLO), 0.f));
              float ik = (pe - back)*e;
              S0[c] += ik;  SY[c] = fmaf(Yae, ik, SY[c]);  tkk = fmaf(e, e, tkk);  rse += ik;
            }
            {
              float nq = fmaf(cX3[c], Yco, ho + cX2[c]);
              float e  = __builtin_amdgcn_exp2f(fminf(fmaxf(nq, NQLO), 0.f));
              float ik = (po - back)*e;
              S0[c] += ik;  SY[c] = fmaf(Yao, ik, SY[c]);  tkk = fmaf(e, e, tkk);  rso += ik;
            }
          }
          tYY = fmaf(Yae*Yae, rse, fmaf(Yao*Yao, rso, tYY));
        }
        float tik = S0[0]+S0[1]+S0[2];
        float tX  = fmaf(Xa[2],S0[2], fmaf(Xa[1],S0[1], Xa[0]*S0[0]));
        float tXX = fmaf(Xa[2]*Xa[2],S0[2], fmaf(Xa[1]*Xa[1],S0[1], (Xa[0]*Xa[0])*S0[0]));
        float tY  = SY[0]+SY[1]+SY[2];
        float tXY = fmaf(Xa[2],SY[2], fmaf(Xa[1],SY[1], Xa[0]*SY[0]));
        tXY=waveSum(tXY); tik=waveSum(tik); tX=waveSum(tX); tY=waveSum(tY);
        tXX=waveSum(tXX); tYY=waveSum(tYY); tkk=waveSum(tkk);
        if (lane == 0){
          wred[0][wave]=tXY; wred[1][wave]=tik; wred[2][wave]=tX; wred[3][wave]=tY;
          wred[4][wave]=tXX; wred[5][wave]=tYY; wred[6][wave]=tkk;
        }
        __syncthreads();
        float T[7];
#pragma unroll
        for (int k = 0; k < 7; ++k){
          float4 r = *reinterpret_cast<const float4*>(&wred[k][0]);
          T[k] = (r.x+r.y)+(r.z+r.w);
        }
        __syncthreads();
        float T1=T[0]*A, T2=T[1]*A, T3=T[2]*A, T4=T[3]*A, T5=T[4]*A, T6=T[5]*A, T7=T[6]*A*A;
        float t2s = fmaxf(fabsf(T2), 1e-6f);
        float rt2 = __builtin_amdgcn_rcpf(t2s);
        float flux = T2 * __builtin_amdgcn_rcpf(fmaxf(T7, 1e-6f));
        back = clampf((total - flux) * (1.f/9216.f), -1.f, 1.f);
        float r3 = T3*rt2, r4 = T4*rt2;
        mux = clampf(r3, -48.f, 48.f);
        muy = clampf(r4, -48.f, 48.f);
        float sxx = clampf(T5*rt2 - r3*r3, 0.25f, 100.f);
        float syy = clampf(T6*rt2 - r4*r4, 0.25f, 100.f);
        float sxy = clampf(T1*rt2 - T3*T4*rt2*rt2, -50.f, 50.f);
        zx = clampf(sxx*2.f, 1.f, 400.f);
        zy = clampf(syy*2.f, 1.f, 400.f);
        axy = clampf(2.f*sxy, -20.f, 20.f);
        float rden = __builtin_amdgcn_rcpf(sxx+syy);
        e1 = clampf((sxx-syy)*rden, -0.95f, 0.95f);
        e2 = clampf(2.f*sxy*rden, -0.95f, 0.95f);
      }
      if (tid == 0) ebuf[d*512 + b] = make_float2(e1, e2);
    } else {
      // barrier skeleton for waves 4,5 — must match active path's count/order
      __syncthreads();
      __syncthreads();
      for (int it = 0; it < 40; ++it){
        __syncthreads();
        __syncthreads();
      }
    }
  } else {
    // ================= conv path (all 384 threads) =================
    float* P   = smem;               // [78*128]
    float* red = smem + 78*128;      // [6]
    const int b = id >> 1, h = id & 1;
    const int R0 = h * 48;

    const float* img = y_pred + (size_t)b * HW;
    for (int u = tid; u < 78*128; u += 384){
      int pr = u >> 7, pc = u & 127;
      int ir = R0 - 15 + pr, ic = pc - 16;
      float v = 0.f;
      if ((unsigned)ir < 96u && (unsigned)ic < 96u) v = img[ir*96 + ic];
      P[u] = v;
    }
    const float* kb = kimg + (size_t)b * 961;
    float ks = 0.f;
    for (int u = tid; u < 961; u += 384) ks += kb[u];
    ks = waveSum(ks);
    if (lane == 0) red[wave] = ks;
    __syncthreads();
    const float inv = __fdividef(1.f, (red[0]+red[1]+red[2]+red[3]+red[4]+red[5]) + 1e-6f);

    const int cs = tid % 24, rq = tid / 24;
    const int c = cs*4;
    const int rr0 = R0 + rq*3;
    float acc[3][4];
#pragma unroll
    for (int q = 0; q < 3; ++q){
#pragma unroll
      for (int j = 0; j < 4; ++j) acc[q][j] = 0.f;
    }

#pragma unroll 1
    for (int s = 0; s < 33; ++s){
      float w[36];
      const float4* prow = reinterpret_cast<const float4*>(&P[(rq*3 + s)*128 + c]);
#pragma unroll
      for (int m = 0; m < 9; ++m){
        float4 v = prow[m];
        w[4*m+0]=v.x; w[4*m+1]=v.y; w[4*m+2]=v.z; w[4*m+3]=v.w;
      }
#pragma unroll
      for (int q = 0; q < 3; ++q){
        const int dy = s - q;
        if (dy >= 0 && dy <= 30){
          const float* kr = kb + dy*31;   // block-uniform -> s_load
#pragma unroll
          for (int dx = 0; dx < 31; ++dx){
            const float kv = kr[dx];
            acc[q][0] = fmaf(kv, w[dx+1], acc[q][0]);
            acc[q][1] = fmaf(kv, w[dx+2], acc[q][1]);
            acc[q][2] = fmaf(kv, w[dx+3], acc[q][2]);
            acc[q][3] = fmaf(kv, w[dx+4], acc[q][3]);
          }
        }
      }
    }

    float lsum = 0.f;
#pragma unroll
    for (int q = 0; q < 3; ++q){
#pragma unroll
      for (int j = 0; j < 4; ++j){
        const int rr = rr0+q, cc = c+j;
        const size_t pix = (size_t)b*HW + rr*96 + cc;
        float ov = acc[q][j] * inv;
        float dd = ov - blurred[2*pix];
        lsum = fmaf(dd*dd, wmap[pix], lsum);
      }
    }
    lsum = waveSum(lsum);
    __syncthreads();
    if (lane == 0) red[wave] = lsum;
    __syncthreads();
    if (tid == 0) convp[id] = red[0]+red[1]+red[2]+red[3]+red[4]+red[5];
  }
}

// ---------------- final combine ----------------
__global__ __launch_bounds__(512) void final_kernel(const float* __restrict__ msep,
                                                    const float* __restrict__ convp,
                                                    const float2* __restrict__ ebuf,
                                                    const int* __restrict__ epoch,
                                                    float* __restrict__ out){
  __shared__ float red[3][8];
  const int tid = threadIdx.x, wave = tid >> 6, lane = tid & 63;
  float a = msep[tid];
  float bsum = convp[tid] + convp[512 + tid];
  float2 et = ebuf[tid], ep = ebuf[512 + tid];
  float dx = et.x - ep.x, dy = et.y - ep.y;
  float c = dx*dx + dy*dy;
  a = waveSum(a); bsum = waveSum(bsum); c = waveSum(c);
  if (lane == 0){ red[0][wave]=a; red[1][wave]=bsum; red[2][wave]=c; }
  __syncthreads();
  if (tid == 0){
    float sa=0, sb=0, sc=0;
#pragma unroll
    for (int w = 0; w < 8; ++w){ sa+=red[0][w]; sb+=red[1][w]; sc+=red[2][w]; }
    float mse   = sa / 4718592.f;
    float rebl  = sb / 4718592.f;
    float ediff = clampf(sc / 512.f, 0.f, 1.f);
    int e = *epoch; if (e > 4) e = 4;
    float ew = 0.01f + 0.1f * (float)e;
    out[0] = 100.f*mse + 100.f*rebl + ew*ediff;
  }
}

extern "C" void kernel_launch(void* const* d_in, const int* in_sizes, int n_in,
                              void* d_out, int out_size, void* d_ws, size_t ws_size,
                              hipStream_t stream){
  const float* y_pred  = (const float*)d_in[0];
  const float* y_true  = (const float*)d_in[1];
  const float* blurred = (const float*)d_in[2];
  const float* kimg    = (const float*)d_in[3];
  const float* wmap    = (const float*)d_in[4];
  const int*   epoch   = (const int*)d_in[5];
  float* out = (float*)d_out;
  float* ws  = (float*)d_ws;

  float*  msep  = ws;                           // 512 floats
  float*  convp = ws + 512;                     // 1024 floats
  float2* ebufp = (float2*)(ws + 1536);         // 1024 float2

  mse_kernel<<<512, 256, 0, stream>>>((const float4*)y_pred, (const float4*)y_true,
                                      (const float4*)wmap, msep);

  fused_kernel<<<2048, 384, 0, stream>>>(y_true, y_pred, kimg, blurred, wmap,
                                         ebufp, convp);

  final_kernel<<<1, 512, 0, stream>>>(msep, convp, ebufp, epoch, out);
}

// Round 12
// 349.374 us; speedup vs baseline: 1.3238x; 1.3238x over previous
//
#include <hip/hip_runtime.h>

#define HW 9216      // 96*96
#define NBATCH 512

__device__ __forceinline__ float clampf(float v, float lo, float hi){ return fminf(fmaxf(v, lo), hi); }

__device__ __forceinline__ float waveSum(float v){
#pragma unroll
  for (int o = 32; o; o >>= 1) v += __shfl_xor(v, o, 64);
  return v;
}

// ---------------- weighted MSE ----------------
__global__ __launch_bounds__(256) void mse_kernel(const float4* __restrict__ yp,
                                                  const float4* __restrict__ yt,
                                                  const float4* __restrict__ wm,
                                                  float* __restrict__ partial){
  __shared__ float red[4];
  const int tid = threadIdx.x;
  int idx = blockIdx.x * 256 + tid;
  float s = 0.f;
#pragma unroll
  for (int u = 0; u < 9; ++u){            // 512 blocks * 256 thr * 9 * 4 = 4718592 elements
    float4 a = yp[idx], b = yt[idx], w = wm[idx];
    float dx = a.x-b.x, dy = a.y-b.y, dz = a.z-b.z, dw = a.w-b.w;
    s += dx*dx*w.x + dy*dy*w.y + dz*dz*w.z + dw*dw*w.w;
    idx += 131072;
  }
  s = waveSum(s);
  if ((tid & 63) == 0) red[tid >> 6] = s;
  __syncthreads();
  if (tid == 0) partial[blockIdx.x] = red[0]+red[1]+red[2]+red[3];
}

// ---------------- FUSED ellipticity + reblur-conv (256-thread blocks) ----------------
// r10/r11 lesson: the allocator's VGPR budget tracks BLOCK SIZE (256thr->64,
// 384thr->40, 512thr->36) and ignores launch_bounds/waves_per_eu/LDS hints.
// The 384-thr fusion therefore spilled ellip's 64-reg live set. Fix: 256-thr
// blocks for BOTH paths. Even bid = ellip (byte-identical r8 path, proven 64
// VGPR no-spill); odd bid = conv retiled to 256 thr: 48-row half-image tile
// [78][126] = 39.3KB LDS (4 blocks/CU), 16 col-strips x 6 cols, 16 row-groups
// x 3 rows (18 px/thread), ds_read_b64 row loads, taps split in two dx-halves
// to keep live w ~22 regs (conv live set ~50 <= 64). Whole-block paths: no
// barrier skeleton needed. Overlap: conv's barrier-free fma stream fills
// ellip's dep/barrier stalls (ellip standalone: 83% VALUBusy, grid-capped 33%
// occupancy).
__global__ __launch_bounds__(256)
void fused_kernel(const float* __restrict__ y_true,
                  const float* __restrict__ y_pred,
                  const float* __restrict__ kimg,
                  const float* __restrict__ blurred,
                  const float* __restrict__ wmap,
                  float2* __restrict__ ebuf,       // [1024]
                  float* __restrict__ convp){      // [1024]
  __shared__ float smem[9832];                     // conv: P[78*126]+red[4]; ellip: wred[7][4]+tred[4]
  typedef __fp16 half2_t __attribute__((ext_vector_type(2)));
  const int tid = threadIdx.x;
  const int bid = blockIdx.x;
  const int id  = bid >> 1;
  const int wave = tid >> 6, lane = tid & 63;

  if ((bid & 1) == 0){
    // ================= ellip path (r8-identical) =================
    float (*wred)[4] = (float(*)[4])smem;          // [7][4]
    float* tred = smem + 28;                       // [4]
    const int d = id >> 9;
    const int b = id & 511;
    const int tx = tid & 31, ty = tid >> 5;        // ty 0..7; rows ty+8k, cols tx+32c

    const float* src = (d ? y_pred : y_true) + (size_t)b * HW + ty * 96 + tx;

    unsigned px2[6][3];
    float tot = 0.f;
#pragma unroll
    for (int jj = 0; jj < 6; ++jj){
#pragma unroll
      for (int c = 0; c < 3; ++c){
        float ve = src[jj*1536 + c*32];
        float vo = src[jj*1536 + 768 + c*32];
        tot += ve + vo;                            // exact f32 total
        half2_t pk = __builtin_amdgcn_cvt_pkrtz(ve, vo);
        unsigned u = __builtin_bit_cast(unsigned, pk);
        asm volatile("" : "+v"(u));                // pin in VGPR (r3 remat fix)
        px2[jj][c] = u;
      }
    }
    tot = waveSum(tot);
    if (lane == 0) tred[wave] = tot;
    __syncthreads();
    float total;
    { float4 t = *reinterpret_cast<const float4*>(&tred[0]); total = (t.x+t.y)+(t.z+t.w); }
    __syncthreads();

    const float Ya00 = (float)ty - 47.5f;
    float Xa[3];
#pragma unroll
    for (int c = 0; c < 3; ++c){ Xa[c] = (float)(tx + 32*c) - 47.5f; }

    float zx=4.f, zy=4.f, axy=0.f, mux=0.f, muy=0.f, back=0.f, e1=0.f, e2=0.f;
    const float LOG2E = 1.4426950408889634f;
    const float NQLO  = -43.280851226668906f;      // -30*log2(e)

    for (int it = 0; it < 40; ++it){
      float axyc = clampf(axy, -10.f, 10.f);
      float prod = zx*zy;
      float adn  = sqrtf(prod);                    // = ax*ay >= 1
      float rca  = __builtin_amdgcn_rcpf(adn);
      float ar   = clampf(axyc*rca, -0.95f, 0.95f);
      float omr  = fmaf(-ar, ar, 1.f);             // >= 0.0975
      float A    = 0.15915494309189535f * rca * __builtin_amdgcn_rsqf(omr);
      float invq = __builtin_amdgcn_rcpf(2.f*omr*prod);
      float a1 = -LOG2E*zy*invq;
      float a2 = -LOG2E*zx*invq;
      float a3 = (2.f*LOG2E)*axyc*invq;
      float cX2[3], cX3[3];
#pragma unroll
      for (int c = 0; c < 3; ++c){
        float Xc = Xa[c] - mux;
        cX2[c] = a1*Xc*Xc;
        cX3[c] = a3*Xc;
      }
      float S0[3] = {0.f,0.f,0.f}, SY[3] = {0.f,0.f,0.f};
      float tYY = 0.f, tkk = 0.f;
#pragma unroll
      for (int jj = 0; jj < 6; ++jj){
        float Yae = Ya00 + 16.f*jj;
        float Yao = Yae + 8.f;
        float Yce = Yae - muy, Yco = Yao - muy;
        float he = a2*Yce*Yce, ho = a2*Yco*Yco;
        float rse = 0.f, rso = 0.f;
#pragma unroll
        for (int c = 0; c < 3; ++c){
          half2_t pk = __builtin_bit_cast(half2_t, px2[jj][c]);
          float pe = (float)pk.x, po = (float)pk.y;
          {
            float nq = fmaf(cX3[c], Yce, he + cX2[c]);
            float e  = __builtin_amdgcn_exp2f(fminf(fmaxf(nq, NQLO), 0.f));
            float ik = (pe - back)*e;
            S0[c] += ik;  SY[c] = fmaf(Yae, ik, SY[c]);  tkk = fmaf(e, e, tkk);  rse += ik;
          }
          {
            float nq = fmaf(cX3[c], Yco, ho + cX2[c]);
            float e  = __builtin_amdgcn_exp2f(fminf(fmaxf(nq, NQLO), 0.f));
            float ik = (po - back)*e;
            S0[c] += ik;  SY[c] = fmaf(Yao, ik, SY[c]);  tkk = fmaf(e, e, tkk);  rso += ik;
          }
        }
        tYY = fmaf(Yae*Yae, rse, fmaf(Yao*Yao, rso, tYY));
      }
      float tik = S0[0]+S0[1]+S0[2];
      float tX  = fmaf(Xa[2],S0[2], fmaf(Xa[1],S0[1], Xa[0]*S0[0]));
      float tXX = fmaf(Xa[2]*Xa[2],S0[2], fmaf(Xa[1]*Xa[1],S0[1], (Xa[0]*Xa[0])*S0[0]));
      float tY  = SY[0]+SY[1]+SY[2];
      float tXY = fmaf(Xa[2],SY[2], fmaf(Xa[1],SY[1], Xa[0]*SY[0]));
      tXY=waveSum(tXY); tik=waveSum(tik); tX=waveSum(tX); tY=waveSum(tY);
      tXX=waveSum(tXX); tYY=waveSum(tYY); tkk=waveSum(tkk);
      if (lane == 0){
        wred[0][wave]=tXY; wred[1][wave]=tik; wred[2][wave]=tX; wred[3][wave]=tY;
        wred[4][wave]=tXX; wred[5][wave]=tYY; wred[6][wave]=tkk;
      }
      __syncthreads();
      float T[7];
#pragma unroll
      for (int k = 0; k < 7; ++k){
        float4 r = *reinterpret_cast<const float4*>(&wred[k][0]);
        T[k] = (r.x+r.y)+(r.z+r.w);
      }
      __syncthreads();
      float T1=T[0]*A, T2=T[1]*A, T3=T[2]*A, T4=T[3]*A, T5=T[4]*A, T6=T[5]*A, T7=T[6]*A*A;
      float t2s = fmaxf(fabsf(T2), 1e-6f);
      float rt2 = __builtin_amdgcn_rcpf(t2s);
      float flux = T2 * __builtin_amdgcn_rcpf(fmaxf(T7, 1e-6f));
      back = clampf((total - flux) * (1.f/9216.f), -1.f, 1.f);
      float r3 = T3*rt2, r4 = T4*rt2;
      mux = clampf(r3, -48.f, 48.f);
      muy = clampf(r4, -48.f, 48.f);
      float sxx = clampf(T5*rt2 - r3*r3, 0.25f, 100.f);
      float syy = clampf(T6*rt2 - r4*r4, 0.25f, 100.f);
      float sxy = clampf(T1*rt2 - T3*T4*rt2*rt2, -50.f, 50.f);
      zx = clampf(sxx*2.f, 1.f, 400.f);
      zy = clampf(syy*2.f, 1.f, 400.f);
      axy = clampf(2.f*sxy, -20.f, 20.f);
      float rden = __builtin_amdgcn_rcpf(sxx+syy);
      e1 = clampf((sxx-syy)*rden, -0.95f, 0.95f);
      e2 = clampf(2.f*sxy*rden, -0.95f, 0.95f);
    }
    if (tid == 0) ebuf[d*512 + b] = make_float2(e1, e2);
  } else {
    // ================= conv path (256 threads) =================
    float* P   = smem;               // [78*126]
    float* red = smem + 9828;        // [4]
    const int b = id >> 1, h = id & 1;
    const int R0 = h * 48;

    const float* img = y_pred + (size_t)b * HW;
    for (int u = tid; u < 78*126; u += 256){
      int pr = u / 126, pc = u - pr*126;
      int ir = R0 - 15 + pr, ic = pc - 15;
      float v = 0.f;
      if ((unsigned)ir < 96u && (unsigned)ic < 96u) v = img[ir*96 + ic];
      P[u] = v;
    }
    const float* kb = kimg + (size_t)b * 961;
    float ks = 0.f;
    for (int u = tid; u < 961; u += 256) ks += kb[u];
    ks = waveSum(ks);
    if (lane == 0) red[wave] = ks;
    __syncthreads();
    const float inv = __fdividef(1.f, (red[0]+red[1]+red[2]+red[3]) + 1e-6f);

    const int strip = tid & 15, rg = tid >> 4;     // 16 strips x 6 cols, 16 rgs x 3 rows
    const int c0 = strip*6;
    const int r0 = R0 + rg*3;
    float acc[3][6];
#pragma unroll
    for (int q = 0; q < 3; ++q){
#pragma unroll
      for (int j = 0; j < 6; ++j) acc[q][j] = 0.f;
    }

#pragma unroll 1
    for (int s = 0; s < 33; ++s){      // LDS row = rg*3 + s; input row = r0 + s - 15
      const float2* prow = reinterpret_cast<const float2*>(&P[(rg*3 + s)*126 + c0]);
      // ---- dx half 0: dx in [0,15], uses w[0..20] ----
      {
        float w[22];
#pragma unroll
        for (int m = 0; m < 11; ++m){ float2 v = prow[m]; w[2*m]=v.x; w[2*m+1]=v.y; }
#pragma unroll
        for (int q = 0; q < 3; ++q){
          const int dy = s - q;
          if (dy >= 0 && dy <= 30){
            const float* kr = kb + dy*31;   // block-uniform -> s_load
#pragma unroll
            for (int dx = 0; dx < 16; ++dx){
              const float kv = kr[dx];
              acc[q][0] = fmaf(kv, w[dx+0], acc[q][0]);
              acc[q][1] = fmaf(kv, w[dx+1], acc[q][1]);
              acc[q][2] = fmaf(kv, w[dx+2], acc[q][2]);
              acc[q][3] = fmaf(kv, w[dx+3], acc[q][3]);
              acc[q][4] = fmaf(kv, w[dx+4], acc[q][4]);
              acc[q][5] = fmaf(kv, w[dx+5], acc[q][5]);
            }
          }
        }
      }
      // ---- dx half 1: dx in [16,30], uses w[16..35] ----
      {
        float w[20];
#pragma unroll
        for (int m = 0; m < 10; ++m){ float2 v = prow[8+m]; w[2*m]=v.x; w[2*m+1]=v.y; }
        // w[k] here = P col c0+16+k  (k=0..19)
#pragma unroll
        for (int q = 0; q < 3; ++q){
          const int dy = s - q;
          if (dy >= 0 && dy <= 30){
            const float* kr = kb + dy*31;
#pragma unroll
            for (int dx = 16; dx < 31; ++dx){
              const float kv = kr[dx];
              acc[q][0] = fmaf(kv, w[dx-16+0], acc[q][0]);
              acc[q][1] = fmaf(kv, w[dx-16+1], acc[q][1]);
              acc[q][2] = fmaf(kv, w[dx-16+2], acc[q][2]);
              acc[q][3] = fmaf(kv, w[dx-16+3], acc[q][3]);
              acc[q][4] = fmaf(kv, w[dx-16+4], acc[q][4]);
              acc[q][5] = fmaf(kv, w[dx-16+5], acc[q][5]);
            }
          }
        }
      }
    }

    float lsum = 0.f;
#pragma unroll
    for (int q = 0; q < 3; ++q){
#pragma unroll
      for (int j = 0; j < 6; ++j){
        const int rr = r0+q, cc = c0+j;
        const size_t pix = (size_t)b*HW + rr*96 + cc;
        float ov = acc[q][j] * inv;
        float dd = ov - blurred[2*pix];
        lsum = fmaf(dd*dd, wmap[pix], lsum);
      }
    }
    lsum = waveSum(lsum);
    __syncthreads();
    if (lane == 0) red[wave] = lsum;
    __syncthreads();
    if (tid == 0) convp[id] = red[0]+red[1]+red[2]+red[3];
  }
}

// ---------------- final combine ----------------
__global__ __launch_bounds__(512) void final_kernel(const float* __restrict__ msep,
                                                    const float* __restrict__ convp,
                                                    const float2* __restrict__ ebuf,
                                                    const int* __restrict__ epoch,
                                                    float* __restrict__ out){
  __shared__ float red[3][8];
  const int tid = threadIdx.x, wave = tid >> 6, lane = tid & 63;
  float a = msep[tid];
  float bsum = convp[tid] + convp[512 + tid];
  float2 et = ebuf[tid], ep = ebuf[512 + tid];
  float dx = et.x - ep.x, dy = et.y - ep.y;
  float c = dx*dx + dy*dy;
  a = waveSum(a); bsum = waveSum(bsum); c = waveSum(c);
  if (lane == 0){ red[0][wave]=a; red[1][wave]=bsum; red[2][wave]=c; }
  __syncthreads();
  if (tid == 0){
    float sa=0, sb=0, sc=0;
#pragma unroll
    for (int w = 0; w < 8; ++w){ sa+=red[0][w]; sb+=red[1][w]; sc+=red[2][w]; }
    float mse   = sa / 4718592.f;
    float rebl  = sb / 4718592.f;
    float ediff = clampf(sc / 512.f, 0.f, 1.f);
    int e = *epoch; if (e > 4) e = 4;
    float ew = 0.01f + 0.1f * (float)e;
    out[0] = 100.f*mse + 100.f*rebl + ew*ediff;
  }
}

extern "C" void kernel_launch(void* const* d_in, const int* in_sizes, int n_in,
                              void* d_out, int out_size, void* d_ws, size_t ws_size,
                              hipStream_t stream){
  const float* y_pred  = (const float*)d_in[0];
  const float* y_true  = (const float*)d_in[1];
  const float* blurred = (const float*)d_in[2];
  const float* kimg    = (const float*)d_in[3];
  const float* wmap    = (const float*)d_in[4];
  const int*   epoch   = (const int*)d_in[5];
  float* out = (float*)d_out;
  float* ws  = (float*)d_ws;

  float*  msep  = ws;                           // 512 floats
  float*  convp = ws + 512;                     // 1024 floats
  float2* ebufp = (float2*)(ws + 1536);         // 1024 float2

  mse_kernel<<<512, 256, 0, stream>>>((const float4*)y_pred, (const float4*)y_true,
                                      (const float4*)wmap, msep);

  fused_kernel<<<2048, 256, 0, stream>>>(y_true, y_pred, kimg, blurred, wmap,
                                         ebufp, convp);

  final_kernel<<<1, 512, 0, stream>>>(msep, convp, ebufp, epoch, out);
}